// Round 1
// baseline (14.925 us; speedup 1.0000x reference)
//
#include <hip/hip_runtime.h>

// WKV power kernel: per-dim linear scan, chunked + wave-parallel.
// T=1024 time steps, D=256 dims. One wave per dim: lane = chunk (64 chunks
// of L=16), Kogge-Stone affine scan across lanes to combine chunk carries.

constexpr int T = 1024;
constexpr int D = 256;
constexpr int L = 16;             // elements per chunk (per lane)
constexpr int C = 64;             // chunks = lanes per wave
constexpr int DIMS_PER_BLOCK = 4; // 4 waves per block, one dim each

__global__ __launch_bounds__(256) void wkv_scan_kernel(
    const float* __restrict__ k, const float* __restrict__ v,
    const float* __restrict__ time_first, const float* __restrict__ time_decay,
    float* __restrict__ out)
{
    const int lane   = threadIdx.x & 63;
    const int waveId = threadIdx.x >> 6;
    const int d      = blockIdx.x * DIMS_PER_BLOCK + waveId;

    const float td = time_decay[d];
    const float w  = __expf(td);            // per-step decay (uniform per wave)
    const float tf = __expf(time_first[d]);

    const int base = lane * L;              // first time index of this chunk

    // ---- Phase 1: local scan seeded with 0; keep kx/vx in registers ----
    float kxv[L], vxv[L];
    float sk = 0.f, sv = 0.f;
#pragma unroll
    for (int it = 0; it < L; ++it) {
        const int i = base + it;
        const float kx = __expf(k[i * D + d]);
        const float vx = v[i * D + d] * kx;
        kxv[it] = kx;
        vxv[it] = vx;
        sk = w * (kx + sk);   // s <- w*(x + s)
        sv = w * (vx + sv);
    }

    // ---- Phase 2: Kogge-Stone inclusive scan of affine transforms over lanes.
    // Chunk transform: s_out = m*s_in + b, with m = w^L, b = local carry.
    // Compose (current) o (earlier): (m_c*m_e, m_c*b_e + b_c).
    float m  = __expf(td * (float)L);       // w^L
    float bk = sk, bv = sv;
#pragma unroll
    for (int o = 1; o < C; o <<= 1) {
        const float pm  = __shfl_up(m, o);
        const float pbk = __shfl_up(bk, o);
        const float pbv = __shfl_up(bv, o);
        if (lane >= o) {
            bk = fmaf(m, pbk, bk);
            bv = fmaf(m, pbv, bv);
            m *= pm;
        }
    }
    // Exclusive prefix: state entering this chunk.
    float pk = __shfl_up(bk, 1);
    float pv = __shfl_up(bv, 1);
    if (lane == 0) { pk = 0.f; pv = 0.f; }

    // ---- Phase 3: re-run local recurrence seeded with prefix; fused output ----
    sk = pk;
    sv = pv;
#pragma unroll
    for (int it = 0; it < L; ++it) {
        sk = w * (kxv[it] + sk);            // = kxr[i]
        sv = w * (vxv[it] + sv);            // = vxr[i]
        const float num = fmaf(vxv[it], tf, sk);  // vx*tf + kxr (faithful swap)
        const float den = fmaf(kxv[it], tf, sv);  // kx*tf + vxr
        out[(base + it) * D + d] = num * __builtin_amdgcn_rcpf(den);
    }
}

extern "C" void kernel_launch(void* const* d_in, const int* in_sizes, int n_in,
                              void* d_out, int out_size, void* d_ws, size_t ws_size,
                              hipStream_t stream) {
    const float* k  = (const float*)d_in[0];
    const float* v  = (const float*)d_in[1];
    const float* tf = (const float*)d_in[2];
    const float* td = (const float*)d_in[3];
    float* out = (float*)d_out;

    dim3 grid(D / DIMS_PER_BLOCK);   // 64 blocks
    dim3 block(256);                 // 4 waves = 4 dims per block
    wkv_scan_kernel<<<grid, block, 0, stream>>>(k, v, tf, td, out);
}

// Round 2
// 11.831 us; speedup vs baseline: 1.2615x; 1.2615x over previous
//
#include <hip/hip_runtime.h>

// WKV power kernel, R2: one dim per block (256 blocks -> all 256 CUs),
// 256 threads/block = 256 chunks of L=4 rows. Per-thread local recurrence,
// intra-wave Kogge-Stone scan (uniform multiplier w^4 -> no M lane-exchange),
// cross-wave combine via tiny LDS, then re-apply with fused output.

constexpr int T = 1024;
constexpr int D = 256;
constexpr int L = 4;              // rows per thread (chunk length)

__global__ __launch_bounds__(256) void wkv_scan_kernel(
    const float* __restrict__ k, const float* __restrict__ v,
    const float* __restrict__ time_first, const float* __restrict__ time_decay,
    float* __restrict__ out)
{
    const int d    = blockIdx.x;          // dim handled by this block
    const int t    = threadIdx.x;         // chunk index 0..255
    const int lane = t & 63;
    const int wv   = t >> 6;              // wave id 0..3

    const float td = time_decay[d];
    const float wd = __expf(td);          // per-row decay w
    const float tf = __expf(time_first[d]);

    const int base = t * L;               // first row of this chunk

    // ---- Phase 1: local recurrence seeded 0; keep kx/vx in registers ----
    float kx[L], vx[L];
    float bk = 0.f, bv = 0.f;
#pragma unroll
    for (int j = 0; j < L; ++j) {
        const float kk = k[(base + j) * D + d];
        const float vv = v[(base + j) * D + d];
        const float e  = __expf(kk);
        kx[j] = e;
        vx[j] = vv * e;
        bk = wd * (kx[j] + bk);           // s <- w*(x + s)
        bv = wd * (vx[j] + bv);
    }

    // ---- Phase 2a: intra-wave inclusive scan. All chunk multipliers equal
    // (m = w^L), so combining a span of o chunks uses factor m^o = f, f *= f.
    float f = __expf(td * (float)L);      // w^L
#pragma unroll
    for (int o = 1; o < 64; o <<= 1) {
        const float pk = __shfl_up(bk, o);
        const float pv = __shfl_up(bv, o);
        if (lane >= o) {
            bk = fmaf(f, pk, bk);
            bv = fmaf(f, pv, bv);
        }
        f = f * f;
    }

    // ---- Phase 2b: cross-wave combine (4 wave totals via LDS) ----
    __shared__ float wbk[4], wbv[4];
    if (lane == 63) { wbk[wv] = bk; wbv[wv] = bv; }
    __syncthreads();
    const float m256 = __expf(td * (float)(L * 64));  // per-wave span decay
    float Pk = 0.f, Pv = 0.f;                         // state entering this wave
    for (int u = 0; u < wv; ++u) {                    // wave-uniform trip count
        Pk = fmaf(m256, Pk, wbk[u]);
        Pv = fmaf(m256, Pv, wbv[u]);
    }

    // Exclusive intra-wave prefix + propagate wave-entry state to this chunk.
    float ek = __shfl_up(bk, 1);
    float ev = __shfl_up(bv, 1);
    if (lane == 0) { ek = 0.f; ev = 0.f; }
    const float mlane = __expf(td * (float)(L * lane)); // w^(L*lane)
    float sk = fmaf(mlane, Pk, ek);       // state entering this chunk
    float sv = fmaf(mlane, Pv, ev);

    // ---- Phase 3: re-run local recurrence seeded with prefix; fused output ----
#pragma unroll
    for (int j = 0; j < L; ++j) {
        sk = wd * (kx[j] + sk);           // = kxr[i]
        sv = wd * (vx[j] + sv);           // = vxr[i]
        const float num = fmaf(vx[j], tf, sk);  // vx*tf + kxr (faithful swap)
        const float den = fmaf(kx[j], tf, sv);  // kx*tf + vxr
        out[(base + j) * D + d] = num * __builtin_amdgcn_rcpf(den);
    }
}

extern "C" void kernel_launch(void* const* d_in, const int* in_sizes, int n_in,
                              void* d_out, int out_size, void* d_ws, size_t ws_size,
                              hipStream_t stream) {
    const float* k  = (const float*)d_in[0];
    const float* v  = (const float*)d_in[1];
    const float* tf = (const float*)d_in[2];
    const float* td = (const float*)d_in[3];
    float* out = (float*)d_out;

    dim3 grid(D);                  // 256 blocks: one dim each -> all CUs
    dim3 block(256);               // 4 waves = 256 chunks of L=4 rows
    wkv_scan_kernel<<<grid, block, 0, stream>>>(k, v, tf, td, out);
}